// Round 1
// baseline (1564.111 us; speedup 1.0000x reference)
//
#include <hip/hip_runtime.h>
#include <hip/hip_bf16.h>
#include <math.h>

// Static feature buffer: 9216 images x 400 feats. Avoids relying on ws_size.
// [0, 1024)      : features of img[n]
// [1024, 9216)   : features of train[refs[n*8+s]] at offset 1024 + n*8 + s
__device__ float g_feat[9216 * 400];

// ---------------------------------------------------------------------------
// Kernel 1: LeNet trunk, one block per image.
// conv1(3->6,k5) relu pool2 -> conv2(6->16,k5) relu pool2 -> flatten 400
// ---------------------------------------------------------------------------
__global__ __launch_bounds__(256) void lenet_kernel(
    const float* __restrict__ img,     // (1024,3,32,32)
    const float* __restrict__ train,   // (50000,3,32,32)
    const int* __restrict__ refs,      // (1024,8)
    const float* __restrict__ w1, const float* __restrict__ b1,  // (6,3,5,5),(6)
    const float* __restrict__ w2, const float* __restrict__ b2)  // (16,6,5,5),(16)
{
    __shared__ float s_in[3 * 32 * 32];   // 3072 (aliased by conv2 output later)
    __shared__ float s_w1[450];
    __shared__ float s_b1[6];
    __shared__ float s_w2[2400];
    __shared__ float s_b2[16];
    __shared__ float s_c1[6 * 28 * 28];   // 4704
    __shared__ float s_p1[6 * 14 * 14];   // 1176
    float* s_c2 = s_in;                   // 16*10*10 = 1600 <= 3072, input dead by then

    const int blk = blockIdx.x;
    const int tid = threadIdx.x;

    const float* src = (blk < 1024)
        ? (img + (size_t)blk * 3072)
        : (train + (size_t)refs[blk - 1024] * 3072);

    for (int i = tid; i < 3072; i += 256) s_in[i] = src[i];
    for (int i = tid; i < 450;  i += 256) s_w1[i] = w1[i];
    for (int i = tid; i < 2400; i += 256) s_w2[i] = w2[i];
    if (tid < 6)  s_b1[tid] = b1[tid];
    if (tid < 16) s_b2[tid] = b2[tid];
    __syncthreads();

    // conv1: 6 x 28 x 28 outputs, 4-wide ox tiles -> 6*28*7 = 1176 tiles
    for (int t = tid; t < 1176; t += 256) {
        const int oc  = t / 196;            // 28 oy * 7 tiles
        const int rem = t - oc * 196;
        const int oy  = rem / 7;
        const int ox4 = (rem - oy * 7) * 4;
        float a0 = s_b1[oc], a1 = a0, a2 = a0, a3 = a0;
        const float* wbase = s_w1 + oc * 75;
        #pragma unroll
        for (int ic = 0; ic < 3; ++ic) {
            const float* ip = s_in + ic * 1024 + oy * 32 + ox4;
            const float* wr = wbase + ic * 25;
            #pragma unroll
            for (int ky = 0; ky < 5; ++ky) {
                const float i0 = ip[0], i1 = ip[1], i2 = ip[2], i3 = ip[3];
                const float i4 = ip[4], i5 = ip[5], i6 = ip[6], i7 = ip[7];
                const float v0 = wr[0], v1 = wr[1], v2 = wr[2], v3 = wr[3], v4 = wr[4];
                a0 += i0 * v0 + i1 * v1 + i2 * v2 + i3 * v3 + i4 * v4;
                a1 += i1 * v0 + i2 * v1 + i3 * v2 + i4 * v3 + i5 * v4;
                a2 += i2 * v0 + i3 * v1 + i4 * v2 + i5 * v3 + i6 * v4;
                a3 += i3 * v0 + i4 * v1 + i5 * v2 + i6 * v3 + i7 * v4;
                ip += 32; wr += 5;
            }
        }
        float* op = s_c1 + oc * 784 + oy * 28 + ox4;
        op[0] = a0; op[1] = a1; op[2] = a2; op[3] = a3;
    }
    __syncthreads();

    // relu + pool1 -> 6 x 14 x 14  (relu(max) == max(relu))
    for (int t = tid; t < 1176; t += 256) {
        const int oc  = t / 196;
        const int rem = t - oc * 196;
        const int py  = rem / 14;
        const int px  = rem - py * 14;
        const float* p = s_c1 + oc * 784 + (2 * py) * 28 + 2 * px;
        const float m = fmaxf(fmaxf(p[0], p[1]), fmaxf(p[28], p[29]));
        s_p1[oc * 196 + py * 14 + px] = fmaxf(m, 0.0f);
    }
    __syncthreads();

    // conv2: 16 x 10 x 10 outputs, 5-wide ox tiles -> 16*10*2 = 320 tiles
    for (int t = tid; t < 320; t += 256) {
        const int oc  = t / 20;             // 10 oy * 2 tiles
        const int rem = t - oc * 20;
        const int oy  = rem / 2;
        const int ox5 = (rem - oy * 2) * 5;
        float a0, a1, a2, a3, a4;
        a0 = a1 = a2 = a3 = a4 = s_b2[oc];
        const float* wbase = s_w2 + oc * 150;
        #pragma unroll
        for (int ic = 0; ic < 6; ++ic) {
            const float* ip = s_p1 + ic * 196 + oy * 14 + ox5;
            const float* wr = wbase + ic * 25;
            #pragma unroll
            for (int ky = 0; ky < 5; ++ky) {
                const float i0 = ip[0], i1 = ip[1], i2 = ip[2], i3 = ip[3], i4 = ip[4];
                const float i5 = ip[5], i6 = ip[6], i7 = ip[7], i8 = ip[8];
                const float v0 = wr[0], v1 = wr[1], v2 = wr[2], v3 = wr[3], v4 = wr[4];
                a0 += i0 * v0 + i1 * v1 + i2 * v2 + i3 * v3 + i4 * v4;
                a1 += i1 * v0 + i2 * v1 + i3 * v2 + i4 * v3 + i5 * v4;
                a2 += i2 * v0 + i3 * v1 + i4 * v2 + i5 * v3 + i6 * v4;
                a3 += i3 * v0 + i4 * v1 + i5 * v2 + i6 * v3 + i7 * v4;
                a4 += i4 * v0 + i5 * v1 + i6 * v2 + i7 * v3 + i8 * v4;
                ip += 14; wr += 5;
            }
        }
        float* op = s_c2 + oc * 100 + oy * 10 + ox5;
        op[0] = a0; op[1] = a1; op[2] = a2; op[3] = a3; op[4] = a4;
    }
    __syncthreads();

    // relu + pool2 -> 16 x 5 x 5 = 400, write feature vector
    float* fo = g_feat + (size_t)blk * 400;
    for (int t = tid; t < 400; t += 256) {
        const int oc  = t / 25;
        const int rem = t - oc * 25;
        const int py  = rem / 5;
        const int px  = rem - py * 5;
        const float* p = s_c2 + oc * 100 + (2 * py) * 10 + 2 * px;
        const float m = fmaxf(fmaxf(p[0], p[1]), fmaxf(p[10], p[11]));
        fo[t] = fmaxf(m, 0.0f);
    }
}

// ---------------------------------------------------------------------------
// Kernel 2: head. One block per n (1024 blocks, 256 threads).
// ---------------------------------------------------------------------------
__global__ __launch_bounds__(256) void head_kernel(
    const float* __restrict__ mem,   // (50000,10)
    const float* __restrict__ Wf, const float* __restrict__ bf,   // (12,400),(12)
    const float* __restrict__ Wg, const float* __restrict__ bg,   // (120,400),(120)
    const float* __restrict__ Wm, const float* __restrict__ bm,   // (10,10),(10)
    const int* __restrict__ refs,    // (1024,8)
    float* __restrict__ out)         // (1024,10)
{
    const int n = blockIdx.x;
    const int tid = threadIdx.x;

    __shared__ float s_feat[400];
    __shared__ float s_rfeat[8 * 400];
    __shared__ float s_x[12];
    __shared__ float s_rx[8 * 12];
    __shared__ float s_grad[120];     // layout h*10 + c
    __shared__ float s_diff[8 * 12];
    __shared__ float s_dist[8];
    __shared__ float s_logits[8 * 10];

    const float* fimg = g_feat + (size_t)n * 400;
    for (int i = tid; i < 400; i += 256) s_feat[i] = fimg[i];
    const float* fref = g_feat + (size_t)1024 * 400 + (size_t)n * 8 * 400;
    for (int i = tid; i < 3200; i += 256) s_rfeat[i] = fref[i];
    __syncthreads();

    // x = Wf @ feat + bf  (threads 0..11)
    if (tid < 12) {
        float a = bf[tid];
        const float* w = Wf + tid * 400;
        for (int k = 0; k < 400; ++k) a += w[k] * s_feat[k];
        s_x[tid] = a;
    }
    // grad = Wg @ feat + bg  (threads 32..151)
    if (tid >= 32 && tid < 152) {
        const int g = tid - 32;
        float a = bg[g];
        const float* w = Wg + g * 400;
        for (int k = 0; k < 400; ++k) a += w[k] * s_feat[k];
        s_grad[g] = a;
    }
    // ref_x = Wf @ rfeat + bf  (threads 160..255 -> 96 = 8*12)
    if (tid >= 160) {
        const int t = tid - 160;
        const int s = t / 12, h = t - s * 12;
        float a = bf[h];
        const float* w = Wf + h * 400;
        const float* f = s_rfeat + s * 400;
        for (int k = 0; k < 400; ++k) a += w[k] * f[k];
        s_rx[t] = a;
    }
    __syncthreads();

    if (tid < 96) {
        const int s = tid / 12, h = tid - s * 12;
        s_diff[tid] = s_x[h] - s_rx[tid];
    }
    __syncthreads();

    // dist logits (wave 0 only: lanes 0..7 then lane 0 softmax — same wave, lockstep)
    if (tid < 8) {
        float nn = 0.0f;
        #pragma unroll
        for (int h = 0; h < 12; ++h) { const float d = s_diff[tid * 12 + h]; nn += d * d; }
        s_dist[tid] = -sqrtf(nn);
    }
    if (tid == 0) {
        float mx = s_dist[0];
        #pragma unroll
        for (int s = 1; s < 8; ++s) mx = fmaxf(mx, s_dist[s]);
        float e[8]; float tot = 0.0f;
        #pragma unroll
        for (int s = 0; s < 8; ++s) { e[s] = expf(s_dist[s] - mx); tot += e[s]; }
        #pragma unroll
        for (int s = 0; s < 8; ++s) s_dist[s] = e[s] / tot;
    }

    // logits[s,c] = mem[refs[n,s]] . Wm[c,:] + bm[c] + sum_h diff[s,h]*grad[h,c]
    if (tid < 80) {
        const int s = tid / 10, c = tid - s * 10;
        const float* mrow = mem + (size_t)refs[n * 8 + s] * 10;
        float a = bm[c];
        #pragma unroll
        for (int k = 0; k < 10; ++k) a += mrow[k] * Wm[c * 10 + k];
        #pragma unroll
        for (int h = 0; h < 12; ++h) a += s_diff[s * 12 + h] * s_grad[h * 10 + c];
        s_logits[tid] = a;
    }
    __syncthreads();

    // out[n,c] = sum_s dist[s] * logits[s,c]   (appended zero row is a no-op)
    if (tid < 10) {
        float a = 0.0f;
        #pragma unroll
        for (int s = 0; s < 8; ++s) a += s_dist[s] * s_logits[s * 10 + tid];
        out[n * 10 + tid] = a;
    }
}

extern "C" void kernel_launch(void* const* d_in, const int* in_sizes, int n_in,
                              void* d_out, int out_size, void* d_ws, size_t ws_size,
                              hipStream_t stream) {
    const float* img   = (const float*)d_in[0];
    const float* train = (const float*)d_in[1];
    const float* mem   = (const float*)d_in[2];
    const float* w1    = (const float*)d_in[3];
    const float* b1    = (const float*)d_in[4];
    const float* w2    = (const float*)d_in[5];
    const float* b2    = (const float*)d_in[6];
    const float* Wf    = (const float*)d_in[7];
    const float* bf    = (const float*)d_in[8];
    const float* Wg    = (const float*)d_in[9];
    const float* bg    = (const float*)d_in[10];
    const float* Wm    = (const float*)d_in[11];
    const float* bm    = (const float*)d_in[12];
    // d_in[13] = idx (unused by the reference)
    const int*   refs  = (const int*)d_in[14];
    float* out = (float*)d_out;

    lenet_kernel<<<9216, 256, 0, stream>>>(img, train, refs, w1, b1, w2, b2);
    head_kernel<<<1024, 256, 0, stream>>>(mem, Wf, bf, Wg, bg, Wm, bm, refs, out);
}